// Round 7
// baseline (658.874 us; speedup 1.0000x reference)
//
#include <hip/hip_runtime.h>

#define D_DIM 256
#define K_CODES 1024
#define HW 4096                  // H*W
#define BDHW 33554432            // 32*256*64*64
#define N_POS 131072             // 32*64*64
#define TAU 0.25f                // ~14 sigma of f16 pair-error

typedef __attribute__((ext_vector_type(8))) _Float16 half8v;
typedef __attribute__((ext_vector_type(4))) float float4v;

__device__ __forceinline__ void load_lds16(const void* g, void* l) {
    __builtin_amdgcn_global_load_lds(
        (const __attribute__((address_space(1))) unsigned int*)g,
        (__attribute__((address_space(3))) unsigned int*)l, 16, 0, 0);
}

// ---------------------------------------------------------------------------
// Kernel 1a: pre-swizzled f16 embT: 64 chunks (nc,dc) of 8 KB whose LINEAR
// image equals the B-LDS layout: byte(r,sp) = r*64 + sp*16 holds
// embed[dc*32 + (sp ^ ((r>>1)&3))*8 + j][nc*128 + r], j=0..7.
// ---------------------------------------------------------------------------
__global__ void vq_prep(const float* __restrict__ embed, uint4* __restrict__ embT) {
    const int c  = blockIdx.x;                   // 64 chunks
    const int nc = c >> 3, dc = c & 7;
    const int t  = threadIdx.x;
#pragma unroll
    for (int i = 0; i < 2; ++i) {
        int p  = i * 256 + t;                    // piece 0..511 (16B each)
        int r  = p >> 2, sp = p & 3;
        int s  = sp ^ ((r >> 1) & 3);
        int k  = nc * 128 + r;
        int db = dc * 32 + s * 8;
        union { _Float16 h[8]; uint4 u; } pk;
#pragma unroll
        for (int j = 0; j < 8; ++j)
            pk.h[j] = (_Float16)embed[(size_t)(db + j) * K_CODES + k];
        embT[c * 512 + p] = pk.u;
    }
}

// ---------------------------------------------------------------------------
// Kernel 1b: enorm[k] = sum_d embed[d][k]^2 (fp32); zero refine counter.
// ---------------------------------------------------------------------------
__global__ void vq_enorm(const float* __restrict__ embed,
                         float* __restrict__ enorm, int* __restrict__ count) {
    __shared__ float part[256];
    const int t = threadIdx.x;
    const int k = blockIdx.x * 128 + (t & 127);
    const int hf = t >> 7;
    float s = 0.f;
#pragma unroll 4
    for (int d = hf * 128; d < hf * 128 + 128; ++d) {
        float e = embed[(size_t)d * K_CODES + k];
        s = fmaf(e, e, s);
    }
    part[t] = s;
    __syncthreads();
    if (t < 128) enorm[k] = part[t] + part[t + 128];
    if (blockIdx.x == 0 && t == 0) *count = 0;
}

// ---------------------------------------------------------------------------
// Kernel 2: f16 MFMA distances + argmin with (min1,idx1,min2).
// 256 thr (4 waves 2Mx2N, wave tile 64 pos x 64 codes), 128 pos x 1024 codes.
// A d<64 in regs; A d in [64,256) in 48 KB swizzled LDS (row 384B).
// B: 3 x 8 KB ring via global_load_lds from pre-swizzled embT.
// Fully-unrolled 64 steps; per step: stage(s+2) -> vmcnt(2) -> barrier ->
// ds_read frags(s+1) [off critical path] || 16 MFMA on frags(s).
// ---------------------------------------------------------------------------
__launch_bounds__(256, 2)
__global__ void vq_argmin(const float* __restrict__ input,
                          const char* __restrict__ embT,
                          const float* __restrict__ enorm,
                          float* __restrict__ indf,
                          int* __restrict__ count,
                          int* __restrict__ list) {
    __shared__ __align__(16) char lds[77824];
    char*  Als = lds;                            // 48 KB: row r -> 384B, slot<24, d=64+slot*8+j
    char*  Bls = lds + 49152;                    // 3 x 8 KB B ring
    float* Els = (float*)(lds + 73728);          // 4 KB enorm

    const int t    = threadIdx.x;
    const int lane = t & 63;
    const int wid  = t >> 6;
    const int blk  = blockIdx.x;                 // 1024 blocks
    const int n0   = blk * 128;
    const int b    = n0 >> 12;
    const int h0   = (n0 & 4095) >> 6;           // rows h0, h0+1
    const int wm = wid >> 1, wn = wid & 1;
    const int l15 = lane & 15, l4 = lane >> 4;

    // ---- prologue: issue B stages for chunks 0,1 (2 x 1KB per wave each)
#pragma unroll
    for (int st = 0; st < 2; ++st) {
        const char* src = embT + (size_t)st * 8192 + wid * 2048 + lane * 16;
        char* dst = Bls + st * 8192 + wid * 2048;
        load_lds16(src, dst);
        load_lds16(src + 1024, dst + 1024);
    }

    // ---- stage enorm to LDS
    *reinterpret_cast<float4*>(Els + t * 4) =
        *reinterpret_cast<const float4*>(enorm + t * 4);

    // ---- stage A d in [64,256) to LDS (coalesced dword loads, b128 writes)
    const float* xbase = input + (size_t)b * (D_DIM * HW) + h0 * 64;
#pragma unroll
    for (int half = 0; half < 2; ++half) {
        const int r = half * 64 + lane;
        const float* hp = xbase + half * 64 + lane;
        const int r7 = lane & 7;
#pragma unroll
        for (int q = 0; q < 6; ++q) {
            const int slot = wid * 6 + q;         // 0..23
            const int d = 64 + slot * 8;
            float v[8];
#pragma unroll
            for (int j = 0; j < 8; ++j) v[j] = hp[(size_t)(d + j) * HW];
            union { _Float16 h[8]; uint4 u; } pk;
#pragma unroll
            for (int j = 0; j < 8; ++j) pk.h[j] = (_Float16)v[j];
            const int byte = r * 384 + (((slot & 24) | ((slot & 7) ^ r7)) << 4);
            *reinterpret_cast<uint4*>(Als + byte) = pk.u;
        }
    }

    // ---- A d<64 directly global -> registers (this wave's 64 pos)
    half8v aR[4][2];                             // [mi][dc], dc<2
    {
        const float* xw = xbase + wm * 64;
#pragma unroll
        for (int dc = 0; dc < 2; ++dc)
#pragma unroll
            for (int mi = 0; mi < 4; ++mi) {
                const float* p = xw + (size_t)(dc * 32 + l4 * 8) * HW + mi * 16 + l15;
                float v[8];
#pragma unroll
                for (int j = 0; j < 8; ++j) v[j] = p[(size_t)j * HW];
                union { _Float16 h[8]; half8v hv; } pk;
#pragma unroll
                for (int j = 0; j < 8; ++j) pk.h[j] = (_Float16)v[j];
                aR[mi][dc] = pk.hv;
            }
    }

    asm volatile("s_waitcnt vmcnt(0) lgkmcnt(0)" ::: "memory");
    __builtin_amdgcn_s_barrier();
    __builtin_amdgcn_sched_barrier(0);

    // fragment addresses
    const int r7a = l15 & 7;                     // (pos row)&7 for A reads
    int aRow[4], bOfs[4];
#pragma unroll
    for (int mi = 0; mi < 4; ++mi) aRow[mi] = (wm * 64 + mi * 16 + l15) * 384;
#pragma unroll
    for (int ni = 0; ni < 4; ++ni) {
        int r = wn * 64 + ni * 16 + l15;
        bOfs[ni] = r * 64 + ((l4 ^ ((r >> 1) & 3)) << 4);
    }

    float m1[4][4], m2[4][4];
    int   i1[4][4];
#pragma unroll
    for (int mi = 0; mi < 4; ++mi)
#pragma unroll
        for (int r = 0; r < 4; ++r) { m1[mi][r] = 3.402823466e38f; m2[mi][r] = 3.402823466e38f; i1[mi][r] = 0; }

    float4v acc[4][4];
    half8v bFc[4], bFn[4], aLc[4], aLn[4];

    // frags for step 0 (chunk 0, dc=0 -> A from regs; B from buf 0)
#pragma unroll
    for (int ni = 0; ni < 4; ++ni)
        bFc[ni] = *reinterpret_cast<const half8v*>(Bls + bOfs[ni]);

#pragma unroll
    for (int ss = 0; ss < 8; ++ss) {
#pragma unroll
        for (int dc = 0; dc < 8; ++dc) {
            const int s = ss * 8 + dc;
            // 1. stage chunk s+2 into ring slot (s+2)%3
            if (s < 62) {
                const char* src = embT + (size_t)(s + 2) * 8192 + wid * 2048 + lane * 16;
                char* dst = Bls + ((s + 2) % 3) * 8192 + wid * 2048;
                load_lds16(src, dst);
                load_lds16(src + 1024, dst + 1024);
            }
            // 2. counted wait: chunk s+1 resident (2 loads of s+2 may fly)
            if (s < 62)      asm volatile("s_waitcnt vmcnt(2)" ::: "memory");
            else if (s == 62) asm volatile("s_waitcnt vmcnt(0)" ::: "memory");
            // 3. one barrier per step
            __builtin_amdgcn_s_barrier();
            // 4. zero acc at chunk start
            if (dc == 0) {
#pragma unroll
                for (int mi = 0; mi < 4; ++mi)
#pragma unroll
                    for (int ni = 0; ni < 4; ++ni) acc[mi][ni] = (float4v){0.f, 0.f, 0.f, 0.f};
            }
            // 5. prefetch next step's fragments (independent of this MFMA)
            if (s < 63) {
                const char* nb = Bls + ((s + 1) % 3) * 8192;
#pragma unroll
                for (int ni = 0; ni < 4; ++ni)
                    bFn[ni] = *reinterpret_cast<const half8v*>(nb + bOfs[ni]);
                if (dc >= 1 && dc <= 6) {        // next dc' = dc+1 in [2,7]: A from LDS
                    const int slot0 = (dc - 1) * 4;
#pragma unroll
                    for (int mi = 0; mi < 4; ++mi) {
                        const int slot = slot0 + l4;
                        aLn[mi] = *reinterpret_cast<const half8v*>(
                            Als + aRow[mi] + (((slot & 24) | ((slot & 7) ^ r7a)) << 4));
                    }
                }
            }
            // 6. MFMA on current fragments
            __builtin_amdgcn_s_setprio(1);
#pragma unroll
            for (int mi = 0; mi < 4; ++mi) {
                half8v aU = (dc == 0) ? aR[mi][0] : (dc == 1) ? aR[mi][1] : aLc[mi];
#pragma unroll
                for (int ni = 0; ni < 4; ++ni)
                    acc[mi][ni] = __builtin_amdgcn_mfma_f32_16x16x32_f16(aU, bFc[ni], acc[mi][ni], 0, 0, 0);
            }
            __builtin_amdgcn_s_setprio(0);
            // 7. rotate
#pragma unroll
            for (int i = 0; i < 4; ++i) bFc[i] = bFn[i];
            if (dc >= 1 && dc <= 6) {
#pragma unroll
                for (int i = 0; i < 4; ++i) aLc[i] = aLn[i];
            }
            // 8. epilogue per 128-code chunk
            if (dc == 7) {
#pragma unroll
                for (int ni = 0; ni < 4; ++ni) {
                    int code = ss * 128 + wn * 64 + ni * 16 + l15;
                    float en = Els[code];
#pragma unroll
                    for (int mi = 0; mi < 4; ++mi)
#pragma unroll
                        for (int r = 0; r < 4; ++r) {
                            float sv = fmaf(-2.f, acc[mi][ni][r], en);
                            if (sv < m1[mi][r]) { m2[mi][r] = m1[mi][r]; m1[mi][r] = sv; i1[mi][r] = code; }
                            else m2[mi][r] = fminf(m2[mi][r], sv);
                        }
                }
            }
        }
    }

    // butterfly across the 16 column-lanes (lex-min on (val, idx), keep min2)
#pragma unroll
    for (int mi = 0; mi < 4; ++mi)
#pragma unroll
        for (int r = 0; r < 4; ++r) {
            float a1 = m1[mi][r], a2 = m2[mi][r]; int ai = i1[mi][r];
#pragma unroll
            for (int m = 8; m >= 1; m >>= 1) {
                float b1 = __shfl_xor(a1, m, 64);
                float b2 = __shfl_xor(a2, m, 64);
                int   bi = __shfl_xor(ai, m, 64);
                bool take = (b1 < a1) || (b1 == a1 && bi < ai);
                float hi = take ? a1 : b1;
                a1 = take ? b1 : a1;
                ai = take ? bi : ai;
                a2 = fminf(fminf(a2, b2), hi);
            }
            m1[mi][r] = a1; m2[mi][r] = a2; i1[mi][r] = ai;
        }

    __syncthreads();                             // done with A/B/enorm; reuse LDS
    float* Lm1 = reinterpret_cast<float*>(lds);  // [2][128]
    float* Lm2 = Lm1 + 256;
    int*   Li1 = reinterpret_cast<int*>(Lm2 + 256);
    if (l15 == 0) {
#pragma unroll
        for (int mi = 0; mi < 4; ++mi)
#pragma unroll
            for (int r = 0; r < 4; ++r) {
                int pos = wm * 64 + mi * 16 + l4 * 4 + r;
                Lm1[wn * 128 + pos] = m1[mi][r];
                Lm2[wn * 128 + pos] = m2[mi][r];
                Li1[wn * 128 + pos] = i1[mi][r];
            }
    }
    __syncthreads();
    if (t < 128) {
        float a1 = Lm1[t], a2 = Lm2[t]; int ai = Li1[t];
        float b1 = Lm1[128 + t], b2 = Lm2[128 + t]; int bi = Li1[128 + t];
        bool take = (b1 < a1) || (b1 == a1 && bi < ai);
        float hi = take ? a1 : b1;
        float f1 = take ? b1 : a1;
        int   fi = take ? bi : ai;
        float f2 = fminf(fminf(a2, b2), hi);
        int n = n0 + t;
        indf[n] = (float)fi;
        if (f2 - f1 < TAU) {                     // near-tie: exact rescan later
            int slot = atomicAdd(count, 1);
            list[slot] = n;
        }
    }
}

// ---------------------------------------------------------------------------
// Kernel 3: exact fp32 rescan — 8 flagged positions per wave.
// Per d: load 16 embed floats/lane once, FMA into 8 position accumulators
// (halves L2 re-reads vs 4-batch). fp32 order and tie-break unchanged.
// ---------------------------------------------------------------------------
__launch_bounds__(256, 2)
__global__ void vq_refine(const float* __restrict__ input,
                          const float* __restrict__ embed,
                          const float* __restrict__ enorm,
                          float* __restrict__ indf,
                          const int* __restrict__ count,
                          const int* __restrict__ list) {
    __shared__ float xls[4][8][D_DIM];
    const int wslot = threadIdx.x >> 6;
    const int lane  = threadIdx.x & 63;
    const int gw    = blockIdx.x * 4 + wslot;
    const int nw    = gridDim.x * 4;
    const int cnt   = *count;
    if (cnt == 0) return;
    const int ngroups = (cnt + 7) >> 3;

    const float* ep = embed + lane * 16;
    float en[16];
    {
        float4 e0 = *reinterpret_cast<const float4*>(enorm + lane * 16);
        float4 e1 = *reinterpret_cast<const float4*>(enorm + lane * 16 + 4);
        float4 e2 = *reinterpret_cast<const float4*>(enorm + lane * 16 + 8);
        float4 e3 = *reinterpret_cast<const float4*>(enorm + lane * 16 + 12);
        en[0]=e0.x; en[1]=e0.y; en[2]=e0.z; en[3]=e0.w;
        en[4]=e1.x; en[5]=e1.y; en[6]=e1.z; en[7]=e1.w;
        en[8]=e2.x; en[9]=e2.y; en[10]=e2.z; en[11]=e2.w;
        en[12]=e3.x; en[13]=e3.y; en[14]=e3.z; en[15]=e3.w;
    }

    for (int g = gw; g < ngroups; g += nw) {
        int np[8];
        const float* bp[8];
#pragma unroll
        for (int p = 0; p < 8; ++p) {
            int li = g * 8 + p; if (li >= cnt) li = cnt - 1;   // tail dup: benign
            np[p] = list[li];
            int b = np[p] >> 12, rem = np[p] & 4095;
            bp[p] = input + (size_t)b * (D_DIM * HW) + rem;
        }
        // cooperative x-load: 32 independent strided lines per lane
#pragma unroll
        for (int j = 0; j < 32; ++j) {
            int p = j >> 2;
            int d = (j & 3) * 64 + lane;
            xls[wslot][p][d] = bp[p][(size_t)d * HW];
        }
        asm volatile("s_waitcnt lgkmcnt(0)" ::: "memory");
        __builtin_amdgcn_sched_barrier(0);

        float acc[8][16];
#pragma unroll
        for (int p = 0; p < 8; ++p)
#pragma unroll
            for (int j = 0; j < 16; ++j) acc[p][j] = 0.f;

        for (int d = 0; d < D_DIM; ++d) {
            const float* er = ep + (size_t)d * K_CODES;
            float4 e0 = *reinterpret_cast<const float4*>(er);
            float4 e1 = *reinterpret_cast<const float4*>(er + 4);
            float4 e2 = *reinterpret_cast<const float4*>(er + 8);
            float4 e3 = *reinterpret_cast<const float4*>(er + 12);
            float ea[16] = {e0.x, e0.y, e0.z, e0.w, e1.x, e1.y, e1.z, e1.w,
                            e2.x, e2.y, e2.z, e2.w, e3.x, e3.y, e3.z, e3.w};
#pragma unroll
            for (int p = 0; p < 8; ++p) {
                float xd = xls[wslot][p][d];
#pragma unroll
                for (int j = 0; j < 16; ++j)
                    acc[p][j] = fmaf(xd, ea[j], acc[p][j]);
            }
        }

#pragma unroll
        for (int p = 0; p < 8; ++p) {
            float bs = 3.402823466e38f; int bk = 0;
#pragma unroll
            for (int j = 0; j < 16; ++j) {
                float s = fmaf(-2.f, acc[p][j], en[j]);
                if (s < bs) { bs = s; bk = lane * 16 + j; }
            }
#pragma unroll
            for (int m = 32; m >= 1; m >>= 1) {
                float os = __shfl_xor(bs, m, 64);
                int   ok = __shfl_xor(bk, m, 64);
                if (os < bs || (os == bs && ok < bk)) { bs = os; bk = ok; }
            }
            if (lane == 0) indf[np[p]] = (float)bk;
        }
        __syncthreads();
    }
}

// ---------------------------------------------------------------------------
// Kernel 4: gather outputs (overwrites the scratch regions last)
// ---------------------------------------------------------------------------
__global__ void vq_gather(const float* __restrict__ embed,
                          const float* __restrict__ indf,
                          float* __restrict__ out0,
                          float* __restrict__ out1) {
    int gid = blockIdx.x * 256 + threadIdx.x;    // BDHW/4 threads
    int w4   = (gid & 15) * 4;
    int rest = gid >> 4;
    int h  = rest & 63;
    int bd = rest >> 6;
    int d  = bd & 255;
    int b  = bd >> 8;
    int n  = (b * 64 + h) * 64 + w4;
    float4 fi = *reinterpret_cast<const float4*>(indf + n);
    const float* erow = embed + (size_t)d * K_CODES;
    float4 q;
    q.x = erow[(int)fi.x];
    q.y = erow[(int)fi.y];
    q.z = erow[(int)fi.z];
    q.w = erow[(int)fi.w];
    size_t o = (size_t)gid * 4;
    *reinterpret_cast<float4*>(out0 + o) = q;
    *reinterpret_cast<float4*>(out1 + o) = q;
}

// ---------------------------------------------------------------------------
extern "C" void kernel_launch(void* const* d_in, const int* in_sizes, int n_in,
                              void* d_out, int out_size, void* d_ws, size_t ws_size,
                              hipStream_t stream) {
    const float* input = (const float*)d_in[0];  // [32, 256, 64, 64] f32
    const float* embed = (const float*)d_in[1];  // [256, 1024] f32
    float* out0 = (float*)d_out;
    float* out1 = out0 + (size_t)BDHW;
    float* indf = out0 + (size_t)2 * BDHW;

    // scratch inside d_out (overwritten by vq_gather at the end):
    uint4* embT  = (uint4*)out0;                 // 512 KB pre-swizzled f16 chunks
    float* enorm = out0 + 131072;                // 4 KB (right after embT)
    int* count = (int*)out1;
    int* list  = (int*)out1 + 1;

    vq_prep  <<<64,          256, 0, stream>>>(embed, embT);
    vq_enorm <<<8,           256, 0, stream>>>(embed, enorm, count);
    vq_argmin<<<N_POS / 128, 256, 0, stream>>>(input, (const char*)embT, enorm, indf, count, list);
    vq_refine<<<256,         256, 0, stream>>>(input, embed, enorm, indf, count, list);
    vq_gather<<<BDHW / 1024, 256, 0, stream>>>(embed, indf, out0, out1);
}

// Round 8
// 331.030 us; speedup vs baseline: 1.9904x; 1.9904x over previous
//
#include <hip/hip_runtime.h>

#define D_DIM 256
#define K_CODES 1024
#define HW 4096                  // H*W
#define BDHW 33554432            // 32*256*64*64
#define N_POS 131072             // 32*64*64
#define TAU 0.25f                // ~14 sigma of f16 pair-error

typedef __attribute__((ext_vector_type(8))) _Float16 half8v;
typedef __attribute__((ext_vector_type(4))) float float4v;

__device__ __forceinline__ void load_lds16(const void* g, void* l) {
    __builtin_amdgcn_global_load_lds(
        (const __attribute__((address_space(1))) unsigned int*)g,
        (__attribute__((address_space(3))) unsigned int*)l, 16, 0, 0);
}

// ---------------------------------------------------------------------------
// Kernel 1a: pre-swizzled f16 embT: 64 chunks (nc,dc) of 8 KB whose LINEAR
// image equals the B-LDS layout: byte(r,sp) = r*64 + sp*16 holds
// embed[dc*32 + (sp ^ ((r>>1)&3))*8 + j][nc*128 + r], j=0..7.
// ---------------------------------------------------------------------------
__global__ void vq_prep(const float* __restrict__ embed, uint4* __restrict__ embT) {
    const int c  = blockIdx.x;                   // 64 chunks
    const int nc = c >> 3, dc = c & 7;
    const int t  = threadIdx.x;
#pragma unroll
    for (int i = 0; i < 2; ++i) {
        int p  = i * 256 + t;                    // piece 0..511 (16B each)
        int r  = p >> 2, sp = p & 3;
        int s  = sp ^ ((r >> 1) & 3);
        int k  = nc * 128 + r;
        int db = dc * 32 + s * 8;
        union { _Float16 h[8]; uint4 u; } pk;
#pragma unroll
        for (int j = 0; j < 8; ++j)
            pk.h[j] = (_Float16)embed[(size_t)(db + j) * K_CODES + k];
        embT[c * 512 + p] = pk.u;
    }
}

// ---------------------------------------------------------------------------
// Kernel 1b: enorm[k] = sum_d embed[d][k]^2 (fp32); zero refine counter.
// ---------------------------------------------------------------------------
__global__ void vq_enorm(const float* __restrict__ embed,
                         float* __restrict__ enorm, int* __restrict__ count) {
    __shared__ float part[256];
    const int t = threadIdx.x;
    const int k = blockIdx.x * 128 + (t & 127);
    const int hf = t >> 7;
    float s = 0.f;
#pragma unroll 4
    for (int d = hf * 128; d < hf * 128 + 128; ++d) {
        float e = embed[(size_t)d * K_CODES + k];
        s = fmaf(e, e, s);
    }
    part[t] = s;
    __syncthreads();
    if (t < 128) enorm[k] = part[t] + part[t + 128];
    if (blockIdx.x == 0 && t == 0) *count = 0;
}

// ---------------------------------------------------------------------------
// Kernel 2: f16 MFMA distances + argmin with (min1,idx1,min2).
// 256 thr (4 waves 2Mx2N, wave tile 64 pos x 64 codes), 128 pos x 1024 codes.
// A d<128 in regs aR[4][4]; A d in [128,256) in 32 KB swizzled LDS.
// B: 4 x 8 KB ring (ring idx compile-time in dc), stage-ahead-2, vmcnt(2).
// dc order {0,4,1,5,2,6,3,7}: even steps use reg-A, odd steps LDS-A -> one
// aL prefetch buffer; B frags double-buffered by parity. All ds_reads are
// issued one step before their MFMA (off critical path). Runtime ss loop
// keeps code size and registers bounded (round-7 spill lesson).
// ---------------------------------------------------------------------------
__launch_bounds__(256, 2)
__global__ void vq_argmin(const float* __restrict__ input,
                          const char* __restrict__ embT,
                          const float* __restrict__ enorm,
                          float* __restrict__ indf,
                          int* __restrict__ count,
                          int* __restrict__ list) {
    __shared__ __align__(16) char lds[69632];
    char*  Als = lds;                            // 32 KB: row r<128 -> 256B, 16 slots, d=128+slot*8+j
    char*  Bls = lds + 32768;                    // 4 x 8 KB B ring
    float* Els = (float*)(lds + 65536);          // 4 KB enorm

    const int t    = threadIdx.x;
    const int lane = t & 63;
    const int wid  = t >> 6;
    const int blk  = blockIdx.x;                 // 1024 blocks
    const int n0   = blk * 128;
    const int b    = n0 >> 12;
    const int h0   = (n0 & 4095) >> 6;           // rows h0, h0+1
    const int wm = wid >> 1, wn = wid & 1;
    const int l15 = lane & 15, l4 = lane >> 4;

    const char* embTw = embT + wid * 2048 + lane * 16;   // per-wave stage base

    // ---- prologue: stage chunks for steps 0,1 (chunk 0 -> slot 0, chunk 4 -> slot 1)
    load_lds16(embTw,                 Bls + wid * 2048);
    load_lds16(embTw + 1024,          Bls + wid * 2048 + 1024);
    load_lds16(embTw + 4 * 8192,      Bls + 8192 + wid * 2048);
    load_lds16(embTw + 4 * 8192 + 1024, Bls + 8192 + wid * 2048 + 1024);

    // ---- stage enorm to LDS
    *reinterpret_cast<float4*>(Els + t * 4) =
        *reinterpret_cast<const float4*>(enorm + t * 4);

    // ---- stage A d in [128,256) to LDS (coalesced dword loads, b128 writes)
    const float* xbase = input + (size_t)b * (D_DIM * HW) + h0 * 64;
#pragma unroll
    for (int half = 0; half < 2; ++half) {
        const int r = half * 64 + lane;
        const float* hp = xbase + half * 64 + lane;
        const int r7 = lane & 7;
#pragma unroll
        for (int q = 0; q < 4; ++q) {
            const int slot = wid * 4 + q;         // 0..15
            const int d = 128 + slot * 8;
            float v[8];
#pragma unroll
            for (int j = 0; j < 8; ++j) v[j] = hp[(size_t)(d + j) * HW];
            union { _Float16 h[8]; uint4 u; } pk;
#pragma unroll
            for (int j = 0; j < 8; ++j) pk.h[j] = (_Float16)v[j];
            const int byte = r * 256 + (((slot & 8) | ((slot & 7) ^ r7)) << 4);
            *reinterpret_cast<uint4*>(Als + byte) = pk.u;
        }
    }

    // ---- A d<128 directly global -> registers (this wave's 64 pos)
    half8v aR[4][4];                             // [mi][dcq], d = dcq*32 + l4*8 + j
    {
        const float* xw = xbase + wm * 64;
#pragma unroll
        for (int dcq = 0; dcq < 4; ++dcq)
#pragma unroll
            for (int mi = 0; mi < 4; ++mi) {
                const float* p = xw + (size_t)(dcq * 32 + l4 * 8) * HW + mi * 16 + l15;
                float v[8];
#pragma unroll
                for (int j = 0; j < 8; ++j) v[j] = p[(size_t)j * HW];
                union { _Float16 h[8]; half8v hv; } pk;
#pragma unroll
                for (int j = 0; j < 8; ++j) pk.h[j] = (_Float16)v[j];
                aR[mi][dcq] = pk.hv;
            }
    }

    asm volatile("s_waitcnt vmcnt(0) lgkmcnt(0)" ::: "memory");
    __builtin_amdgcn_s_barrier();
    __builtin_amdgcn_sched_barrier(0);

    // fragment base addresses (single regs; per-frag deltas are immediates)
    const int r7a = l15 & 7;
    const int A0 = (wm * 64 + l15) * 256;                      // + mi*4096 + swz<<4
    const int B0 = wn * 4096 + l15 * 64 + ((l4 ^ ((l15 >> 1) & 3)) << 4); // + ni*1024

    float m1[4][4], m2[4][4];
    int   i1[4][4];
#pragma unroll
    for (int mi = 0; mi < 4; ++mi)
#pragma unroll
        for (int r = 0; r < 4; ++r) { m1[mi][r] = 3.402823466e38f; m2[mi][r] = 3.402823466e38f; i1[mi][r] = 0; }

    float4v acc[4][4];
    half8v bF[2][4], aL[4];

    // frags for step 0 (chunk 0, ring slot 0, reg-A)
#pragma unroll
    for (int ni = 0; ni < 4; ++ni)
        bF[0][ni] = *reinterpret_cast<const half8v*>(Bls + B0 + ni * 1024);

    constexpr int ORD[8] = {0, 4, 1, 5, 2, 6, 3, 7};

    for (int ss = 0; ss < 8; ++ss) {
#pragma unroll
        for (int i = 0; i < 8; ++i) {
            // 1. stage chunk for step g+2 into ring slot (i+2)&3
            if (ss < 7 || i < 6) {
                const int cb = (i < 6) ? ss : ss + 1;
                const int chunk = cb * 8 + ORD[(i + 2) & 7];
                const char* src = embTw + (size_t)chunk * 8192;
                char* dst = Bls + ((i + 2) & 3) * 8192 + wid * 2048;
                load_lds16(src, dst);
                load_lds16(src + 1024, dst + 1024);
            }
            // 2. counted wait: chunk for step g+1 resident (2 newest may fly)
            if (ss < 7 || i < 6)  asm volatile("s_waitcnt vmcnt(2)" ::: "memory");
            else if (i == 6)      asm volatile("s_waitcnt vmcnt(0)" ::: "memory");
            // 3. one barrier per step
            __builtin_amdgcn_s_barrier();
            // 4. zero acc at chunk start
            if (i == 0) {
#pragma unroll
                for (int mi = 0; mi < 4; ++mi)
#pragma unroll
                    for (int ni = 0; ni < 4; ++ni) acc[mi][ni] = (float4v){0.f, 0.f, 0.f, 0.f};
            }
            // 5. prefetch next step's fragments (consumed next step)
            if (ss < 7 || i < 7) {
                const char* nb = Bls + ((i + 1) & 3) * 8192;
#pragma unroll
                for (int ni = 0; ni < 4; ++ni)
                    bF[(i + 1) & 1][ni] = *reinterpret_cast<const half8v*>(nb + B0 + ni * 1024);
                if ((i & 1) == 0) {               // next dc = ORD[i+1] in {4..7}: LDS-A
                    const int slot0 = (ORD[i + 1] - 4) * 4;
                    const int slot = slot0 + l4;
                    const int swz = ((slot & 8) | ((slot & 7) ^ r7a)) << 4;
#pragma unroll
                    for (int mi = 0; mi < 4; ++mi)
                        aL[mi] = *reinterpret_cast<const half8v*>(Als + A0 + mi * 4096 + swz);
                }
            }
            // 6. MFMA on current fragments (all already in registers)
            __builtin_amdgcn_s_setprio(1);
#pragma unroll
            for (int mi = 0; mi < 4; ++mi) {
                half8v aU = ((i & 1) == 0) ? aR[mi][i >> 1] : aL[mi];
#pragma unroll
                for (int ni = 0; ni < 4; ++ni)
                    acc[mi][ni] = __builtin_amdgcn_mfma_f32_16x16x32_f16(aU, bF[i & 1][ni], acc[mi][ni], 0, 0, 0);
            }
            __builtin_amdgcn_s_setprio(0);
            // 7. epilogue per 128-code chunk
            if (i == 7) {
#pragma unroll
                for (int ni = 0; ni < 4; ++ni) {
                    int code = ss * 128 + wn * 64 + ni * 16 + l15;
                    float en = Els[code];
#pragma unroll
                    for (int mi = 0; mi < 4; ++mi)
#pragma unroll
                        for (int r = 0; r < 4; ++r) {
                            float sv = fmaf(-2.f, acc[mi][ni][r], en);
                            if (sv < m1[mi][r]) { m2[mi][r] = m1[mi][r]; m1[mi][r] = sv; i1[mi][r] = code; }
                            else m2[mi][r] = fminf(m2[mi][r], sv);
                        }
                }
            }
        }
    }

    // butterfly across the 16 column-lanes (lex-min on (val, idx), keep min2)
#pragma unroll
    for (int mi = 0; mi < 4; ++mi)
#pragma unroll
        for (int r = 0; r < 4; ++r) {
            float a1 = m1[mi][r], a2 = m2[mi][r]; int ai = i1[mi][r];
#pragma unroll
            for (int m = 8; m >= 1; m >>= 1) {
                float b1 = __shfl_xor(a1, m, 64);
                float b2 = __shfl_xor(a2, m, 64);
                int   bi = __shfl_xor(ai, m, 64);
                bool take = (b1 < a1) || (b1 == a1 && bi < ai);
                float hi = take ? a1 : b1;
                a1 = take ? b1 : a1;
                ai = take ? bi : ai;
                a2 = fminf(fminf(a2, b2), hi);
            }
            m1[mi][r] = a1; m2[mi][r] = a2; i1[mi][r] = ai;
        }

    __syncthreads();                             // done with A/B/enorm; reuse LDS
    float* Lm1 = reinterpret_cast<float*>(lds);  // [2][128]
    float* Lm2 = Lm1 + 256;
    int*   Li1 = reinterpret_cast<int*>(Lm2 + 256);
    if (l15 == 0) {
#pragma unroll
        for (int mi = 0; mi < 4; ++mi)
#pragma unroll
            for (int r = 0; r < 4; ++r) {
                int pos = wm * 64 + mi * 16 + l4 * 4 + r;
                Lm1[wn * 128 + pos] = m1[mi][r];
                Lm2[wn * 128 + pos] = m2[mi][r];
                Li1[wn * 128 + pos] = i1[mi][r];
            }
    }
    __syncthreads();
    if (t < 128) {
        float a1 = Lm1[t], a2 = Lm2[t]; int ai = Li1[t];
        float b1 = Lm1[128 + t], b2 = Lm2[128 + t]; int bi = Li1[128 + t];
        bool take = (b1 < a1) || (b1 == a1 && bi < ai);
        float hi = take ? a1 : b1;
        float f1 = take ? b1 : a1;
        int   fi = take ? bi : ai;
        float f2 = fminf(fminf(a2, b2), hi);
        int n = n0 + t;
        indf[n] = (float)fi;
        if (f2 - f1 < TAU) {                     // near-tie: exact rescan later
            int slot = atomicAdd(count, 1);
            list[slot] = n;
        }
    }
}

// ---------------------------------------------------------------------------
// Kernel 3: exact fp32 rescan — 8 flagged positions per wave.
// ---------------------------------------------------------------------------
__launch_bounds__(256, 2)
__global__ void vq_refine(const float* __restrict__ input,
                          const float* __restrict__ embed,
                          const float* __restrict__ enorm,
                          float* __restrict__ indf,
                          const int* __restrict__ count,
                          const int* __restrict__ list) {
    __shared__ float xls[4][8][D_DIM];
    const int wslot = threadIdx.x >> 6;
    const int lane  = threadIdx.x & 63;
    const int gw    = blockIdx.x * 4 + wslot;
    const int nw    = gridDim.x * 4;
    const int cnt   = *count;
    if (cnt == 0) return;
    const int ngroups = (cnt + 7) >> 3;

    const float* ep = embed + lane * 16;
    float en[16];
    {
        float4 e0 = *reinterpret_cast<const float4*>(enorm + lane * 16);
        float4 e1 = *reinterpret_cast<const float4*>(enorm + lane * 16 + 4);
        float4 e2 = *reinterpret_cast<const float4*>(enorm + lane * 16 + 8);
        float4 e3 = *reinterpret_cast<const float4*>(enorm + lane * 16 + 12);
        en[0]=e0.x; en[1]=e0.y; en[2]=e0.z; en[3]=e0.w;
        en[4]=e1.x; en[5]=e1.y; en[6]=e1.z; en[7]=e1.w;
        en[8]=e2.x; en[9]=e2.y; en[10]=e2.z; en[11]=e2.w;
        en[12]=e3.x; en[13]=e3.y; en[14]=e3.z; en[15]=e3.w;
    }

    for (int g = gw; g < ngroups; g += nw) {
        int np[8];
        const float* bp[8];
#pragma unroll
        for (int p = 0; p < 8; ++p) {
            int li = g * 8 + p; if (li >= cnt) li = cnt - 1;   // tail dup: benign
            np[p] = list[li];
            int b = np[p] >> 12, rem = np[p] & 4095;
            bp[p] = input + (size_t)b * (D_DIM * HW) + rem;
        }
        // cooperative x-load: 32 independent strided lines per lane
#pragma unroll
        for (int j = 0; j < 32; ++j) {
            int p = j >> 2;
            int d = (j & 3) * 64 + lane;
            xls[wslot][p][d] = bp[p][(size_t)d * HW];
        }
        asm volatile("s_waitcnt lgkmcnt(0)" ::: "memory");
        __builtin_amdgcn_sched_barrier(0);

        float acc[8][16];
#pragma unroll
        for (int p = 0; p < 8; ++p)
#pragma unroll
            for (int j = 0; j < 16; ++j) acc[p][j] = 0.f;

        for (int d = 0; d < D_DIM; ++d) {
            const float* er = ep + (size_t)d * K_CODES;
            float4 e0 = *reinterpret_cast<const float4*>(er);
            float4 e1 = *reinterpret_cast<const float4*>(er + 4);
            float4 e2 = *reinterpret_cast<const float4*>(er + 8);
            float4 e3 = *reinterpret_cast<const float4*>(er + 12);
            float ea[16] = {e0.x, e0.y, e0.z, e0.w, e1.x, e1.y, e1.z, e1.w,
                            e2.x, e2.y, e2.z, e2.w, e3.x, e3.y, e3.z, e3.w};
#pragma unroll
            for (int p = 0; p < 8; ++p) {
                float xd = xls[wslot][p][d];
#pragma unroll
                for (int j = 0; j < 16; ++j)
                    acc[p][j] = fmaf(xd, ea[j], acc[p][j]);
            }
        }

#pragma unroll
        for (int p = 0; p < 8; ++p) {
            float bs = 3.402823466e38f; int bk = 0;
#pragma unroll
            for (int j = 0; j < 16; ++j) {
                float s = fmaf(-2.f, acc[p][j], en[j]);
                if (s < bs) { bs = s; bk = lane * 16 + j; }
            }
#pragma unroll
            for (int m = 32; m >= 1; m >>= 1) {
                float os = __shfl_xor(bs, m, 64);
                int   ok = __shfl_xor(bk, m, 64);
                if (os < bs || (os == bs && ok < bk)) { bs = os; bk = ok; }
            }
            if (lane == 0) indf[np[p]] = (float)bk;
        }
        __syncthreads();
    }
}

// ---------------------------------------------------------------------------
// Kernel 4: gather outputs (overwrites the scratch regions last)
// ---------------------------------------------------------------------------
__global__ void vq_gather(const float* __restrict__ embed,
                          const float* __restrict__ indf,
                          float* __restrict__ out0,
                          float* __restrict__ out1) {
    int gid = blockIdx.x * 256 + threadIdx.x;    // BDHW/4 threads
    int w4   = (gid & 15) * 4;
    int rest = gid >> 4;
    int h  = rest & 63;
    int bd = rest >> 6;
    int d  = bd & 255;
    int b  = bd >> 8;
    int n  = (b * 64 + h) * 64 + w4;
    float4 fi = *reinterpret_cast<const float4*>(indf + n);
    const float* erow = embed + (size_t)d * K_CODES;
    float4 q;
    q.x = erow[(int)fi.x];
    q.y = erow[(int)fi.y];
    q.z = erow[(int)fi.z];
    q.w = erow[(int)fi.w];
    size_t o = (size_t)gid * 4;
    *reinterpret_cast<float4*>(out0 + o) = q;
    *reinterpret_cast<float4*>(out1 + o) = q;
}

// ---------------------------------------------------------------------------
extern "C" void kernel_launch(void* const* d_in, const int* in_sizes, int n_in,
                              void* d_out, int out_size, void* d_ws, size_t ws_size,
                              hipStream_t stream) {
    const float* input = (const float*)d_in[0];  // [32, 256, 64, 64] f32
    const float* embed = (const float*)d_in[1];  // [256, 1024] f32
    float* out0 = (float*)d_out;
    float* out1 = out0 + (size_t)BDHW;
    float* indf = out0 + (size_t)2 * BDHW;

    // scratch inside d_out (overwritten by vq_gather at the end):
    uint4* embT  = (uint4*)out0;                 // 512 KB pre-swizzled f16 chunks
    float* enorm = out0 + 131072;                // 4 KB (right after embT)
    int* count = (int*)out1;
    int* list  = (int*)out1 + 1;

    vq_prep  <<<64,          256, 0, stream>>>(embed, embT);
    vq_enorm <<<8,           256, 0, stream>>>(embed, enorm, count);
    vq_argmin<<<N_POS / 128, 256, 0, stream>>>(input, (const char*)embT, enorm, indf, count, list);
    vq_refine<<<256,         256, 0, stream>>>(input, embed, enorm, indf, count, list);
    vq_gather<<<BDHW / 1024, 256, 0, stream>>>(embed, indf, out0, out1);
}

// Round 9
// 307.846 us; speedup vs baseline: 2.1403x; 1.0753x over previous
//
#include <hip/hip_runtime.h>

#define D_DIM 256
#define K_CODES 1024
#define HW 4096                  // H*W
#define BDHW 33554432            // 32*256*64*64
#define N_POS 131072             // 32*64*64
#define TAU 0.25f                // ~14 sigma of f16 pair-error

typedef __attribute__((ext_vector_type(8))) _Float16 half8v;
typedef __attribute__((ext_vector_type(4))) float float4v;

__device__ __forceinline__ void load_lds16(const void* g, void* l) {
    __builtin_amdgcn_global_load_lds(
        (const __attribute__((address_space(1))) unsigned int*)g,
        (__attribute__((address_space(3))) unsigned int*)l, 16, 0, 0);
}

// ---------------------------------------------------------------------------
// Kernel 1a: pre-swizzled f16 embT: 64 chunks (nc,dc) of 8 KB whose LINEAR
// image equals the B-LDS layout: byte(r,sp) = r*64 + sp*16 holds
// embed[dc*32 + (sp ^ ((r>>1)&3))*8 + j][nc*128 + r], j=0..7.
// ---------------------------------------------------------------------------
__global__ void vq_prep(const float* __restrict__ embed, uint4* __restrict__ embT) {
    const int c  = blockIdx.x;                   // 64 chunks
    const int nc = c >> 3, dc = c & 7;
    const int t  = threadIdx.x;
#pragma unroll
    for (int i = 0; i < 2; ++i) {
        int p  = i * 256 + t;                    // piece 0..511 (16B each)
        int r  = p >> 2, sp = p & 3;
        int s  = sp ^ ((r >> 1) & 3);
        int k  = nc * 128 + r;
        int db = dc * 32 + s * 8;
        union { _Float16 h[8]; uint4 u; } pk;
#pragma unroll
        for (int j = 0; j < 8; ++j)
            pk.h[j] = (_Float16)embed[(size_t)(db + j) * K_CODES + k];
        embT[c * 512 + p] = pk.u;
    }
}

// ---------------------------------------------------------------------------
// Kernel 1b: enorm[k] = sum_d embed[d][k]^2 (fp32); zero refine counter.
// ---------------------------------------------------------------------------
__global__ void vq_enorm(const float* __restrict__ embed,
                         float* __restrict__ enorm, int* __restrict__ count) {
    __shared__ float part[256];
    const int t = threadIdx.x;
    const int k = blockIdx.x * 128 + (t & 127);
    const int hf = t >> 7;
    float s = 0.f;
#pragma unroll 4
    for (int d = hf * 128; d < hf * 128 + 128; ++d) {
        float e = embed[(size_t)d * K_CODES + k];
        s = fmaf(e, e, s);
    }
    part[t] = s;
    __syncthreads();
    if (t < 128) enorm[k] = part[t] + part[t + 128];
    if (blockIdx.x == 0 && t == 0) *count = 0;
}

// ---------------------------------------------------------------------------
// Kernel 2: f16 MFMA distances + argmin with (min1,idx1,min2).
// 256 thr (4 waves 2Mx2N, wave tile 64 pos x 64 codes), 128 pos x 1024 codes.
// FAT STEPS: K=64 per barrier -> 32 steps, 32 MFMA/step.
// A d<64 in regs aR[4][2] (32 VGPR); A d in [64,256) in 48 KB swizzled LDS.
// B: 2 x 16 KB ring; stage(s+1) issued AFTER barrier(s) (race-free: barrier
// proves all waves finished reading buf (s-1)&1 == (s+1)&1); one vmcnt(0)
// per step, covered by a full step of compute. No persistent frag buffers
// (rounds 7-8 spill lesson): peak regs ~210.
// ---------------------------------------------------------------------------
__launch_bounds__(256, 2)
__global__ void vq_argmin(const float* __restrict__ input,
                          const char* __restrict__ embT,
                          const float* __restrict__ enorm,
                          float* __restrict__ indf,
                          int* __restrict__ count,
                          int* __restrict__ list) {
    __shared__ __align__(16) char lds[81920];
    char* Als = lds;                             // 48 KB: row r -> 384B, slots 0..23, d = 64+slot*8+j
    char* Bls = lds + 49152;                     // 2 x 16 KB B ring (two 8 KB sub-chunks each)

    const int t    = threadIdx.x;
    const int lane = t & 63;
    const int wid  = t >> 6;
    const int blk  = blockIdx.x;                 // 1024 blocks
    const int n0   = blk * 128;
    const int b    = n0 >> 12;
    const int h0   = (n0 & 4095) >> 6;           // rows h0, h0+1
    const int wm = wid >> 1, wn = wid & 1;
    const int l15 = lane & 15, l4 = lane >> 4;

    const char* embTw = embT + wid * 2048 + lane * 16;   // per-wave stage base

    // stage 16 KB for step s into ring buf (s&1): chunks 2s, 2s+1
#define STAGE(sname) {                                                        \
        const char* src = embTw + (size_t)(2 * (sname)) * 8192;               \
        char* dst = Bls + (((sname) & 1) << 14) + wid * 2048;                 \
        load_lds16(src,               dst);                                   \
        load_lds16(src + 1024,        dst + 1024);                            \
        load_lds16(src + 8192,        dst + 8192);                            \
        load_lds16(src + 8192 + 1024, dst + 8192 + 1024); }

    // ---- prologue: stage step 0
    STAGE(0);

    // ---- stage A d in [64,256) to LDS (coalesced dword loads, b128 writes)
    const float* xbase = input + (size_t)b * (D_DIM * HW) + h0 * 64;
#pragma unroll
    for (int half = 0; half < 2; ++half) {
        const int r = half * 64 + lane;
        const float* hp = xbase + half * 64 + lane;
        const int r7 = lane & 7;
#pragma unroll
        for (int q = 0; q < 6; ++q) {
            const int slot = wid * 6 + q;         // 0..23
            const int d = 64 + slot * 8;
            float v[8];
#pragma unroll
            for (int j = 0; j < 8; ++j) v[j] = hp[(size_t)(d + j) * HW];
            union { _Float16 h[8]; uint4 u; } pk;
#pragma unroll
            for (int j = 0; j < 8; ++j) pk.h[j] = (_Float16)v[j];
            const int byte = r * 384 + (((slot & 24) | ((slot & 7) ^ r7)) << 4);
            *reinterpret_cast<uint4*>(Als + byte) = pk.u;
        }
    }

    // ---- A d<64 directly global -> registers (this wave's 64 pos)
    half8v aR[4][2];                             // [mi][ksub], d = ksub*32 + l4*8 + j
    {
        const float* xw = xbase + wm * 64;
#pragma unroll
        for (int ks = 0; ks < 2; ++ks)
#pragma unroll
            for (int mi = 0; mi < 4; ++mi) {
                const float* p = xw + (size_t)(ks * 32 + l4 * 8) * HW + mi * 16 + l15;
                float v[8];
#pragma unroll
                for (int j = 0; j < 8; ++j) v[j] = p[(size_t)j * HW];
                union { _Float16 h[8]; half8v hv; } pk;
#pragma unroll
                for (int j = 0; j < 8; ++j) pk.h[j] = (_Float16)v[j];
                aR[mi][ks] = pk.hv;
            }
    }

    // fragment base addresses
    const int r7a = l15 & 7;
    const int A0 = (wm * 64 + l15) * 384;                      // + mi*6144 + swz
    const int B0 = wn * 4096 + l15 * 64 + ((l4 ^ ((l15 >> 1) & 3)) << 4); // + ni*1024 (+ ks*8192)

    float m1[4][4], m2[4][4];
    int   i1[4][4];
#pragma unroll
    for (int mi = 0; mi < 4; ++mi)
#pragma unroll
        for (int r = 0; r < 4; ++r) { m1[mi][r] = 3.402823466e38f; m2[mi][r] = 3.402823466e38f; i1[mi][r] = 0; }

    float4v acc[4][4];
    float enE[4];

    for (int ss = 0; ss < 8; ++ss) {             // 8 nc chunks of 128 codes
#pragma unroll
        for (int i = 0; i < 4; ++i) {            // 4 fat K=64 steps per chunk
            const int s = ss * 4 + i;
            // stage(s) landed? (issued one full step ago, except s=0: prologue)
            asm volatile("s_waitcnt vmcnt(0)" ::: "memory");
            __builtin_amdgcn_s_barrier();
            __builtin_amdgcn_sched_barrier(0);
            // issue stage(s+1) into buf (s+1)&1 — safe: barrier proved all
            // waves are done reading that buffer (their step-(s-1) frag reads
            // retired before their barrier arrival).
            if (s < 31) STAGE(s + 1);
            if (i == 0) {
#pragma unroll
                for (int mi = 0; mi < 4; ++mi)
#pragma unroll
                    for (int ni = 0; ni < 4; ++ni) acc[mi][ni] = (float4v){0.f, 0.f, 0.f, 0.f};
#pragma unroll
                for (int ni = 0; ni < 4; ++ni)
                    enE[ni] = enorm[ss * 128 + wn * 64 + ni * 16 + l15];
            }
            const char* curB = Bls + ((i & 1) << 14);   // s&1 == i&1
            __builtin_amdgcn_s_setprio(1);
#pragma unroll
            for (int ks = 0; ks < 2; ++ks) {
                half8v bF[4], aF[4];
#pragma unroll
                for (int ni = 0; ni < 4; ++ni)
                    bF[ni] = *reinterpret_cast<const half8v*>(curB + ks * 8192 + B0 + ni * 1024);
                if (i == 0) {
#pragma unroll
                    for (int mi = 0; mi < 4; ++mi) aF[mi] = aR[mi][ks];
                } else {
                    const int slot = (i - 1) * 8 + ks * 4 + l4;
                    const int swz = ((slot & 24) | ((slot & 7) ^ r7a)) << 4;
#pragma unroll
                    for (int mi = 0; mi < 4; ++mi)
                        aF[mi] = *reinterpret_cast<const half8v*>(Als + A0 + mi * 6144 + swz);
                }
#pragma unroll
                for (int mi = 0; mi < 4; ++mi)
#pragma unroll
                    for (int ni = 0; ni < 4; ++ni)
                        acc[mi][ni] = __builtin_amdgcn_mfma_f32_16x16x32_f16(aF[mi], bF[ni], acc[mi][ni], 0, 0, 0);
            }
            __builtin_amdgcn_s_setprio(0);
            if (i == 3) {                        // epilogue per 128-code chunk
#pragma unroll
                for (int ni = 0; ni < 4; ++ni) {
                    int code = ss * 128 + wn * 64 + ni * 16 + l15;
#pragma unroll
                    for (int mi = 0; mi < 4; ++mi)
#pragma unroll
                        for (int r = 0; r < 4; ++r) {
                            float sv = fmaf(-2.f, acc[mi][ni][r], enE[ni]);
                            if (sv < m1[mi][r]) { m2[mi][r] = m1[mi][r]; m1[mi][r] = sv; i1[mi][r] = code; }
                            else m2[mi][r] = fminf(m2[mi][r], sv);
                        }
                }
            }
        }
    }
#undef STAGE

    // butterfly across the 16 column-lanes (lex-min on (val, idx), keep min2)
#pragma unroll
    for (int mi = 0; mi < 4; ++mi)
#pragma unroll
        for (int r = 0; r < 4; ++r) {
            float a1 = m1[mi][r], a2 = m2[mi][r]; int ai = i1[mi][r];
#pragma unroll
            for (int m = 8; m >= 1; m >>= 1) {
                float b1 = __shfl_xor(a1, m, 64);
                float b2 = __shfl_xor(a2, m, 64);
                int   bi = __shfl_xor(ai, m, 64);
                bool take = (b1 < a1) || (b1 == a1 && bi < ai);
                float hi = take ? a1 : b1;
                a1 = take ? b1 : a1;
                ai = take ? bi : ai;
                a2 = fminf(fminf(a2, b2), hi);
            }
            m1[mi][r] = a1; m2[mi][r] = a2; i1[mi][r] = ai;
        }

    __syncthreads();                             // done with A/B; reuse LDS
    float* Lm1 = reinterpret_cast<float*>(lds);  // [2][128]
    float* Lm2 = Lm1 + 256;
    int*   Li1 = reinterpret_cast<int*>(Lm2 + 256);
    if (l15 == 0) {
#pragma unroll
        for (int mi = 0; mi < 4; ++mi)
#pragma unroll
            for (int r = 0; r < 4; ++r) {
                int pos = wm * 64 + mi * 16 + l4 * 4 + r;
                Lm1[wn * 128 + pos] = m1[mi][r];
                Lm2[wn * 128 + pos] = m2[mi][r];
                Li1[wn * 128 + pos] = i1[mi][r];
            }
    }
    __syncthreads();
    if (t < 128) {
        float a1 = Lm1[t], a2 = Lm2[t]; int ai = Li1[t];
        float b1 = Lm1[128 + t], b2 = Lm2[128 + t]; int bi = Li1[128 + t];
        bool take = (b1 < a1) || (b1 == a1 && bi < ai);
        float hi = take ? a1 : b1;
        float f1 = take ? b1 : a1;
        int   fi = take ? bi : ai;
        float f2 = fminf(fminf(a2, b2), hi);
        int n = n0 + t;
        indf[n] = (float)fi;
        if (f2 - f1 < TAU) {                     // near-tie: exact rescan later
            int slot = atomicAdd(count, 1);
            list[slot] = n;
        }
    }
}

// ---------------------------------------------------------------------------
// Kernel 3: exact fp32 rescan — 8 flagged positions per wave.
// ---------------------------------------------------------------------------
__launch_bounds__(256, 2)
__global__ void vq_refine(const float* __restrict__ input,
                          const float* __restrict__ embed,
                          const float* __restrict__ enorm,
                          float* __restrict__ indf,
                          const int* __restrict__ count,
                          const int* __restrict__ list) {
    __shared__ float xls[4][8][D_DIM];
    const int wslot = threadIdx.x >> 6;
    const int lane  = threadIdx.x & 63;
    const int gw    = blockIdx.x * 4 + wslot;
    const int nw    = gridDim.x * 4;
    const int cnt   = *count;
    if (cnt == 0) return;
    const int ngroups = (cnt + 7) >> 3;

    const float* ep = embed + lane * 16;
    float en[16];
    {
        float4 e0 = *reinterpret_cast<const float4*>(enorm + lane * 16);
        float4 e1 = *reinterpret_cast<const float4*>(enorm + lane * 16 + 4);
        float4 e2 = *reinterpret_cast<const float4*>(enorm + lane * 16 + 8);
        float4 e3 = *reinterpret_cast<const float4*>(enorm + lane * 16 + 12);
        en[0]=e0.x; en[1]=e0.y; en[2]=e0.z; en[3]=e0.w;
        en[4]=e1.x; en[5]=e1.y; en[6]=e1.z; en[7]=e1.w;
        en[8]=e2.x; en[9]=e2.y; en[10]=e2.z; en[11]=e2.w;
        en[12]=e3.x; en[13]=e3.y; en[14]=e3.z; en[15]=e3.w;
    }

    for (int g = gw; g < ngroups; g += nw) {
        int np[8];
        const float* bp[8];
#pragma unroll
        for (int p = 0; p < 8; ++p) {
            int li = g * 8 + p; if (li >= cnt) li = cnt - 1;   // tail dup: benign
            np[p] = list[li];
            int b = np[p] >> 12, rem = np[p] & 4095;
            bp[p] = input + (size_t)b * (D_DIM * HW) + rem;
        }
        // cooperative x-load: 32 independent strided lines per lane
#pragma unroll
        for (int j = 0; j < 32; ++j) {
            int p = j >> 2;
            int d = (j & 3) * 64 + lane;
            xls[wslot][p][d] = bp[p][(size_t)d * HW];
        }
        asm volatile("s_waitcnt lgkmcnt(0)" ::: "memory");
        __builtin_amdgcn_sched_barrier(0);

        float acc[8][16];
#pragma unroll
        for (int p = 0; p < 8; ++p)
#pragma unroll
            for (int j = 0; j < 16; ++j) acc[p][j] = 0.f;

        for (int d = 0; d < D_DIM; ++d) {
            const float* er = ep + (size_t)d * K_CODES;
            float4 e0 = *reinterpret_cast<const float4*>(er);
            float4 e1 = *reinterpret_cast<const float4*>(er + 4);
            float4 e2 = *reinterpret_cast<const float4*>(er + 8);
            float4 e3 = *reinterpret_cast<const float4*>(er + 12);
            float ea[16] = {e0.x, e0.y, e0.z, e0.w, e1.x, e1.y, e1.z, e1.w,
                            e2.x, e2.y, e2.z, e2.w, e3.x, e3.y, e3.z, e3.w};
#pragma unroll
            for (int p = 0; p < 8; ++p) {
                float xd = xls[wslot][p][d];
#pragma unroll
                for (int j = 0; j < 16; ++j)
                    acc[p][j] = fmaf(xd, ea[j], acc[p][j]);
            }
        }

#pragma unroll
        for (int p = 0; p < 8; ++p) {
            float bs = 3.402823466e38f; int bk = 0;
#pragma unroll
            for (int j = 0; j < 16; ++j) {
                float s = fmaf(-2.f, acc[p][j], en[j]);
                if (s < bs) { bs = s; bk = lane * 16 + j; }
            }
#pragma unroll
            for (int m = 32; m >= 1; m >>= 1) {
                float os = __shfl_xor(bs, m, 64);
                int   ok = __shfl_xor(bk, m, 64);
                if (os < bs || (os == bs && ok < bk)) { bs = os; bk = ok; }
            }
            if (lane == 0) indf[np[p]] = (float)bk;
        }
        __syncthreads();
    }
}

// ---------------------------------------------------------------------------
// Kernel 4: gather outputs (overwrites the scratch regions last)
// ---------------------------------------------------------------------------
__global__ void vq_gather(const float* __restrict__ embed,
                          const float* __restrict__ indf,
                          float* __restrict__ out0,
                          float* __restrict__ out1) {
    int gid = blockIdx.x * 256 + threadIdx.x;    // BDHW/4 threads
    int w4   = (gid & 15) * 4;
    int rest = gid >> 4;
    int h  = rest & 63;
    int bd = rest >> 6;
    int d  = bd & 255;
    int b  = bd >> 8;
    int n  = (b * 64 + h) * 64 + w4;
    float4 fi = *reinterpret_cast<const float4*>(indf + n);
    const float* erow = embed + (size_t)d * K_CODES;
    float4 q;
    q.x = erow[(int)fi.x];
    q.y = erow[(int)fi.y];
    q.z = erow[(int)fi.z];
    q.w = erow[(int)fi.w];
    size_t o = (size_t)gid * 4;
    *reinterpret_cast<float4*>(out0 + o) = q;
    *reinterpret_cast<float4*>(out1 + o) = q;
}

// ---------------------------------------------------------------------------
extern "C" void kernel_launch(void* const* d_in, const int* in_sizes, int n_in,
                              void* d_out, int out_size, void* d_ws, size_t ws_size,
                              hipStream_t stream) {
    const float* input = (const float*)d_in[0];  // [32, 256, 64, 64] f32
    const float* embed = (const float*)d_in[1];  // [256, 1024] f32
    float* out0 = (float*)d_out;
    float* out1 = out0 + (size_t)BDHW;
    float* indf = out0 + (size_t)2 * BDHW;

    // scratch inside d_out (overwritten by vq_gather at the end):
    uint4* embT  = (uint4*)out0;                 // 512 KB pre-swizzled f16 chunks
    float* enorm = out0 + 131072;                // 4 KB (right after embT)
    int* count = (int*)out1;
    int* list  = (int*)out1 + 1;

    vq_prep  <<<64,          256, 0, stream>>>(embed, embT);
    vq_enorm <<<8,           256, 0, stream>>>(embed, enorm, count);
    vq_argmin<<<N_POS / 128, 256, 0, stream>>>(input, (const char*)embT, enorm, indf, count, list);
    vq_refine<<<256,         256, 0, stream>>>(input, embed, enorm, indf, count, list);
    vq_gather<<<BDHW / 1024, 256, 0, stream>>>(embed, indf, out0, out1);
}